// Round 19
// baseline (219.578 us; speedup 1.0000x reference)
//
#include <hip/hip_runtime.h>

#define NMS_NUM_CLASSES 16
#define NMS_N 2048
#define NMS_IOU_TH 0.5f
#define NMS_SCORE_TH 0.05f
#define NMS_MAX_DET 100
#define NMS_MAX_PER_CLASS 100
#define NMS_NS (NMS_NUM_CLASSES * NMS_MAX_PER_CLASS)   // 1600
#define NMS_TILE 128
#define NMS_TW 4                     // u32 words per column mask (128 bits)
#define NMS_REPS 4                   // DIAGNOSTIC: amplify k1 body 4x to
                                     // split fixed-per-dispatch vs work cost

// SESSION PITFALLS (r1-r18):
//  * float4 casts on __shared__ float -> ds_read_b128 misalignment fault.
//  * u64 LDS arrays / LDS pointer casts correlated with container deaths.
//    ONLY declared __shared__ float/uint/uchar arrays, scalar access.
//  * Serial NMS chains cost 45-65 us at M~122 -> Jacobi fixpoint (r15).
//  * Fusion via grid.sync REGRESSED (+5us): launch gaps ~1.4us in graphs.
//  * k1 measures ~39us but bottom-up phase model says ~7us -> this round
//    is a x4 amplification diagnostic: k1(4x) = F + 4W, F + W = 39.

// ---------------------------------------------------------------------------
// Kernel 1: one block per (image, class), 1024 threads. r18 body (passed,
// absmax 0) wrapped in an idempotent NMS_REPS loop.
// ---------------------------------------------------------------------------
__global__ __launch_bounds__(1024) void nms_per_class_kernel(
    const float* __restrict__ pred,   // [B, N, 6] x1,y1,x2,y2,cls,score
    float* __restrict__ ws_scores,    // [B, 1600]
    float* __restrict__ ws_boxes,     // [B, 1600, 4]
    float* __restrict__ out,          // [B*600] rows + [B] nvalid
    int B)
{
    const int b = blockIdx.x / NMS_NUM_CLASSES;
    const int c = blockIdx.x % NMS_NUM_CLASSES;
    const float* p = pred + (size_t)b * NMS_N * 6;

    // zero-init output for this image (k2 is a later dispatch on the stream)
    if (c == 0) {
        float* ob = out + (size_t)b * NMS_MAX_DET * 6;
        for (int t = threadIdx.x; t < NMS_MAX_DET * 6; t += blockDim.x) ob[t] = 0.0f;
        if (threadIdx.x == 0) out[(size_t)B * NMS_MAX_DET * 6 + b] = 0.0f;
    }

    // unsorted candidate arrays
    __shared__ float s_scu[NMS_N];
    __shared__ int   s_ixu[NMS_N];
    __shared__ float s_bxu[NMS_N * 4];
    __shared__ int   s_rk[NMS_N];
    // sorted candidate arrays
    __shared__ float s_sc[NMS_N];
    __shared__ float s_bx[NMS_N * 4];
    __shared__ unsigned char s_keep[NMS_N];
    __shared__ unsigned int s_supc[NMS_TILE * NMS_TW];  // column masks, 2 KB
    __shared__ unsigned int s_kwds[NMS_TW];             // published keep bits
    __shared__ int s_m;
    __shared__ int s_part[256];
    __shared__ int s_total;
    __shared__ int s_chg;

    for (int rep = 0; rep < NMS_REPS; ++rep) {
    __syncthreads();                 // hygiene: prior rep fully drained
    if (threadIdx.x == 0) s_m = 0;
    __syncthreads();

    // --- wave-aggregated compact of class-c candidates (score > TH) ---
    const float2* p2 = (const float2*)p;   // row i = p2[3i], p2[3i+1], p2[3i+2]
    for (int i = threadIdx.x; i < NMS_N; i += blockDim.x) {   // uniform trips
        float2 v0 = p2[i * 3 + 0];   // x1, y1
        float2 v1 = p2[i * 3 + 1];   // x2, y2
        float2 v2 = p2[i * 3 + 2];   // cls, score
        const bool ok = ((int)v2.x == c) && (v2.y > NMS_SCORE_TH);
        unsigned long long mask = __ballot(ok);
        const int lane = threadIdx.x & 63;
        int base = 0;
        if (lane == 0) {
            int cnt = __popcll(mask);
            if (cnt) base = atomicAdd(&s_m, cnt);
        }
        base = __shfl(base, 0, 64);
        if (ok) {
            int pos = base + __popcll(mask & ((1ull << lane) - 1ull));
            s_scu[pos] = v2.y;
            s_ixu[pos] = i;
            s_bxu[pos * 4 + 0] = v0.x;
            s_bxu[pos * 4 + 1] = v0.y;
            s_bxu[pos * 4 + 2] = v1.x;
            s_bxu[pos * 4 + 3] = v1.y;
        }
    }
    __syncthreads();
    const int M = s_m;

    // --- task-parallel rank sort (r16-proven) ---
    for (int q = threadIdx.x; q < M; q += blockDim.x) s_rk[q] = 0;
    __syncthreads();
    {
        const int nch = (M + 31) >> 5;
        const int ntask = M * nch;
        for (int task = threadIdx.x; task < ntask; task += blockDim.x) {
            const int q = task % M;          // consecutive tids -> distinct q
            const int ch = task / M;
            const float sq = s_scu[q];
            const int   iq = s_ixu[q];
            const int j0 = ch << 5;
            int jend = j0 + 32; if (jend > M) jend = M;
            int rk = 0;
            for (int j = j0; j < jend; ++j) {
                float sj = s_scu[j];
                rk += (sj > sq) || (sj == sq && s_ixu[j] < iq);
            }
            if (rk) atomicAdd(&s_rk[q], rk);
        }
    }
    __syncthreads();
    for (int q = threadIdx.x; q < M; q += blockDim.x) {
        int rk = s_rk[q];
        s_sc[rk] = s_scu[q];
        s_bx[rk * 4 + 0] = s_bxu[q * 4 + 0];
        s_bx[rk * 4 + 1] = s_bxu[q * 4 + 1];
        s_bx[rk * 4 + 2] = s_bxu[q * 4 + 2];
        s_bx[rk * 4 + 3] = s_bxu[q * 4 + 3];
        s_keep[rk] = 1;
    }
    __syncthreads();

    // --- tiled NMS: column masks + Jacobi fixpoint per tile (r15-proven) ---
    for (int t0 = 0; t0 < M; t0 += NMS_TILE) {
        const int tm = (M - t0 < NMS_TILE) ? (M - t0) : NMS_TILE;

        // A0: suppression by kept candidates of earlier tiles (final state)
        if (t0 > 0) {
            for (int j = threadIdx.x; j < tm; j += blockDim.x) {
                const int gj = t0 + j;
                float jx1 = s_bx[gj * 4 + 0], jy1 = s_bx[gj * 4 + 1];
                float jx2 = s_bx[gj * 4 + 2], jy2 = s_bx[gj * 4 + 3];
                float aj = (jy2 - jy1) * (jx2 - jx1);
                int dead = 0;
                for (int i = 0; i < t0 && !dead; ++i) {
                    if (!s_keep[i]) continue;
                    float ix1 = s_bx[i * 4 + 0], iy1 = s_bx[i * 4 + 1];
                    float ix2 = s_bx[i * 4 + 2], iy2 = s_bx[i * 4 + 3];
                    float ai = (iy2 - iy1) * (ix2 - ix1);
                    float ih = fminf(iy2, jy2) - fmaxf(iy1, jy1);
                    ih = fmaxf(ih, 0.0f);
                    float iw = fminf(ix2, jx2) - fmaxf(ix1, jx1);
                    iw = fmaxf(iw, 0.0f);
                    float inter = ih * iw;
                    float uni = ai + aj - inter;
                    float iou = (inter > 0.0f) ? inter / fmaxf(uni, 1e-08f) : 0.0f;
                    dead = iou > NMS_IOU_TH;
                }
                if (dead) s_keep[gj] = 0;
            }
            __syncthreads();
        }

        // A: column suppressor masks — (wi, j) task space in one sweep
        for (int idx = threadIdx.x; idx < NMS_TW * tm; idx += blockDim.x) {
            const int wi = idx / tm;
            const int j = idx % tm;
            const int ibase = wi << 5;
            unsigned int msk = 0;
            int iend = j - ibase;            // only i < j
            if (iend > 32) iend = 32;
            if (iend > 0) {
                const int gj = t0 + j;
                float jx1 = s_bx[gj * 4 + 0], jy1 = s_bx[gj * 4 + 1];
                float jx2 = s_bx[gj * 4 + 2], jy2 = s_bx[gj * 4 + 3];
                float aj = (jy2 - jy1) * (jx2 - jx1);
                for (int bb = 0; bb < iend; ++bb) {
                    const int gi = t0 + ibase + bb;
                    float ix1 = s_bx[gi * 4 + 0], iy1 = s_bx[gi * 4 + 1];
                    float ix2 = s_bx[gi * 4 + 2], iy2 = s_bx[gi * 4 + 3];
                    float ai = (iy2 - iy1) * (ix2 - ix1);
                    float ih = fminf(iy2, jy2) - fmaxf(iy1, jy1);
                    ih = fmaxf(ih, 0.0f);
                    float iw = fminf(ix2, jx2) - fmaxf(ix1, jx1);
                    iw = fmaxf(iw, 0.0f);
                    float inter = ih * iw;
                    float uni = ai + aj - inter;
                    float iou = (inter > 0.0f) ? inter / fmaxf(uni, 1e-08f) : 0.0f;
                    if (iou > NMS_IOU_TH) msk |= (1u << bb);
                }
            }
            s_supc[j * NMS_TW + wi] = msk;
        }

        // Jacobi init: thread j owns tile candidate j
        const int j = threadIdx.x;
        int ext = 0;                 // pre-suppression state (A0 deaths final)
        if (j < tm) ext = s_keep[t0 + j];
        int alive = ext;
        __syncthreads();             // supc complete

        {
            unsigned long long bal = __ballot(alive != 0);
            if ((threadIdx.x & 63) == 0 && threadIdx.x < NMS_TILE) {
                s_kwds[(threadIdx.x >> 6) * 2 + 0] = (unsigned int)(bal & 0xffffffffu);
                s_kwds[(threadIdx.x >> 6) * 2 + 1] = (unsigned int)(bal >> 32);
            }
            if (threadIdx.x == 0) s_chg = 0;
        }
        __syncthreads();

        int prev = 0;
        for (int round = 0; round < tm; ++round) {
            int newalive = 0;
            if (j < tm && ext) {
                unsigned int any = (s_supc[j * NMS_TW + 0] & s_kwds[0])
                                 | (s_supc[j * NMS_TW + 1] & s_kwds[1])
                                 | (s_supc[j * NMS_TW + 2] & s_kwds[2])
                                 | (s_supc[j * NMS_TW + 3] & s_kwds[3]);
                newalive = (any == 0);
            }
            int ch = (newalive != alive);
            alive = newalive;
            __syncthreads();                       // kwds reads done
            {
                unsigned long long bal = __ballot(alive != 0);
                if ((threadIdx.x & 63) == 0 && threadIdx.x < NMS_TILE) {
                    s_kwds[(threadIdx.x >> 6) * 2 + 0] = (unsigned int)(bal & 0xffffffffu);
                    s_kwds[(threadIdx.x >> 6) * 2 + 1] = (unsigned int)(bal >> 32);
                }
                if (ch) atomicAdd(&s_chg, 1);
            }
            __syncthreads();                       // kwds + counter visible
            int cur = s_chg;
            if (cur == prev) break;                // uniform decision
            prev = cur;
        }

        if (j < tm) s_keep[t0 + j] = (unsigned char)alive;
        __syncthreads();
    }

    // --- emit top-100 kept in sorted order (first 256 threads) ---
    const int chunk = (M + 255) / 256;           // contiguous slots per thread
    int lo = 0, hi = 0;
    if (threadIdx.x < 256) {
        lo = threadIdx.x * chunk;
        hi = (lo + chunk < M) ? (lo + chunk) : M;
        int cnt = 0;
        for (int jj = lo; jj < hi; ++jj) cnt += s_keep[jj];
        s_part[threadIdx.x] = cnt;
    }
    __syncthreads();
    if (threadIdx.x < 64) {
        const int base = threadIdx.x * 4;
        int v0 = s_part[base + 0], v1 = s_part[base + 1];
        int v2 = s_part[base + 2], v3 = s_part[base + 3];
        int sum = v0 + v1 + v2 + v3;
        int inc = sum;
        for (int off = 1; off < 64; off <<= 1) {
            int n = __shfl_up(inc, off, 64);
            if ((int)threadIdx.x >= off) inc += n;
        }
        int exc = inc - sum;
        s_part[base + 0] = exc;
        s_part[base + 1] = exc + v0;
        s_part[base + 2] = exc + v0 + v1;
        s_part[base + 3] = exc + v0 + v1 + v2;
        if (threadIdx.x == 63) s_total = inc;
    }
    __syncthreads();

    float* osc = ws_scores + ((size_t)b * NMS_NUM_CLASSES + c) * NMS_MAX_PER_CLASS;
    float* obx = ws_boxes + (((size_t)b * NMS_NUM_CLASSES + c) * NMS_MAX_PER_CLASS) * 4;
    if (threadIdx.x < 256) {
        int pos = s_part[threadIdx.x];
        for (int jj = lo; jj < hi; ++jj) {
            if (s_keep[jj]) {
                if (pos < NMS_MAX_PER_CLASS) {
                    osc[pos] = s_sc[jj];
                    obx[pos * 4 + 0] = s_bx[jj * 4 + 0];
                    obx[pos * 4 + 1] = s_bx[jj * 4 + 1];
                    obx[pos * 4 + 2] = s_bx[jj * 4 + 2];
                    obx[pos * 4 + 3] = s_bx[jj * 4 + 3];
                }
                pos++;
            }
        }
    }
    // pad positions [total, 100) with -1
    if (threadIdx.x < NMS_MAX_PER_CLASS && threadIdx.x >= s_total)
        osc[threadIdx.x] = -1.0f;
    }   // rep loop
}

// ---------------------------------------------------------------------------
// Kernel 2: one block per (image, class), 256 threads. Task-parallel partial
// ranks. BYTE-IDENTICAL to round-12 (passed, absmax 0).
// ---------------------------------------------------------------------------
__global__ __launch_bounds__(256) void nms_topk_kernel(
    const float* __restrict__ ws_scores,   // [B, 1600]
    const float* __restrict__ ws_boxes,    // [B, 1600, 4]
    float* __restrict__ out,               // [B*600] rows + [B] nvalid
    int B)
{
    const int b = blockIdx.x / NMS_NUM_CLASSES;
    const int c = blockIdx.x % NMS_NUM_CLASSES;
    const int cbase = c * NMS_MAX_PER_CLASS;
    __shared__ float s_sc[NMS_NS];
    __shared__ int s_rank[NMS_MAX_PER_CLASS];

    const float* isc = ws_scores + (size_t)b * NMS_NS;
    for (int t = threadIdx.x; t < NMS_NS; t += blockDim.x) s_sc[t] = isc[t];
    if (threadIdx.x < NMS_MAX_PER_CLASS) s_rank[threadIdx.x] = 0;
    __syncthreads();

    for (int task = threadIdx.x; task < NMS_MAX_PER_CLASS * 16; task += blockDim.x) {
        const int slot = task % NMS_MAX_PER_CLASS;
        const int chunk = task / NMS_MAX_PER_CLASS;
        const int flat = cbase + slot;
        const float s = s_sc[flat];
        const int j0 = chunk * 100;
        int rk = 0;
        for (int j = j0; j < j0 + 100; ++j) {
            float sj = s_sc[j];
            rk += (sj > s) || (sj == s && j < flat);
        }
        if (rk) atomicAdd(&s_rank[slot], rk);
    }
    __syncthreads();

    int is_top = 0;
    const int t = threadIdx.x;
    if (t < NMS_MAX_PER_CLASS) {
        const int slot = cbase + t;
        float s = s_sc[slot];
        if (s > NMS_SCORE_TH) {
            int rk = s_rank[t];
            if (rk < NMS_MAX_DET) {
                const float* bx = ws_boxes + ((size_t)b * NMS_NS + slot) * 4;
                float* row = out + (size_t)b * NMS_MAX_DET * 6 + rk * 6;
                row[0] = bx[0];
                row[1] = bx[1];
                row[2] = bx[2];
                row[3] = bx[3];
                row[4] = (float)c;
                row[5] = s;
                is_top = 1;
            }
        }
    }
    unsigned long long m = __ballot(is_top);
    if ((threadIdx.x & 63) == 0) {
        float cnt = (float)__popcll(m);
        if (cnt > 0.0f)
            atomicAdd(&out[(size_t)B * NMS_MAX_DET * 6 + b], cnt);
    }
}

extern "C" void kernel_launch(void* const* d_in, const int* in_sizes, int n_in,
                              void* d_out, int out_size, void* d_ws, size_t ws_size,
                              hipStream_t stream) {
    const float* pred = (const float*)d_in[0];
    const int B = in_sizes[0] / (NMS_N * 6);
    if (B <= 0) return;
    float* out = (float*)d_out;

    float* ws_scores = (float*)d_ws;
    float* ws_boxes = ws_scores + (size_t)B * NMS_NS;

    nms_per_class_kernel<<<dim3(B * NMS_NUM_CLASSES), dim3(1024), 0, stream>>>(
        pred, ws_scores, ws_boxes, out, B);
    nms_topk_kernel<<<dim3(B * NMS_NUM_CLASSES), dim3(256), 0, stream>>>(
        ws_scores, ws_boxes, out, B);
}

// Round 20
// 111.848 us; speedup vs baseline: 1.9632x; 1.9632x over previous
//
#include <hip/hip_runtime.h>

#define NMS_NUM_CLASSES 16
#define NMS_N 2048
#define NMS_IOU_TH 0.5f
#define NMS_SCORE_TH 0.05f
#define NMS_MAX_DET 100
#define NMS_MAX_PER_CLASS 100
#define NMS_NS (NMS_NUM_CLASSES * NMS_MAX_PER_CLASS)   // 1600
#define NMS_TILE 128
#define NMS_TW 4                     // u32 words per column mask (128 bits)

// SESSION PITFALLS (r1-r19):
//  * float4 casts on __shared__ float -> ds_read_b128 misalignment fault.
//  * u64 LDS arrays / LDS pointer casts correlated with container deaths.
//    ONLY declared __shared__ float/uint/uchar arrays, scalar access.
//  * Serial NMS chains cost 45-65 us at M~122 -> Jacobi fixpoint (r15).
//  * Fusion via grid.sync REGRESSED (+5us): launch gaps ~1.4us in graphs.
//  * r19 amplification: k1 = F + W with F~2us, W~37us -> the cost is real
//    phase work (latency-bound: VALU issue ~5us, stall ~32us across ~15
//    barrier phases), not dispatch overhead. This round: cut 2 phases.

// ---------------------------------------------------------------------------
// Kernel 1: one block per (image, class), 1024 threads.
// Wave-aggregated compact (+ fused s_rk zeroing) -> task-parallel rank sort
// -> column-mask + Jacobi NMS -> wave-scan emit.
// ---------------------------------------------------------------------------
__global__ __launch_bounds__(1024) void nms_per_class_kernel(
    const float* __restrict__ pred,   // [B, N, 6] x1,y1,x2,y2,cls,score
    float* __restrict__ ws_scores,    // [B, 1600]
    float* __restrict__ ws_boxes,     // [B, 1600, 4]
    float* __restrict__ out,          // [B*600] rows + [B] nvalid
    int B)
{
    const int b = blockIdx.x / NMS_NUM_CLASSES;
    const int c = blockIdx.x % NMS_NUM_CLASSES;
    const float* p = pred + (size_t)b * NMS_N * 6;

    // zero-init output for this image (k2 is a later dispatch on the stream)
    if (c == 0) {
        float* ob = out + (size_t)b * NMS_MAX_DET * 6;
        for (int t = threadIdx.x; t < NMS_MAX_DET * 6; t += blockDim.x) ob[t] = 0.0f;
        if (threadIdx.x == 0) out[(size_t)B * NMS_MAX_DET * 6 + b] = 0.0f;
    }

    // unsorted candidate arrays
    __shared__ float s_scu[NMS_N];
    __shared__ int   s_ixu[NMS_N];
    __shared__ float s_bxu[NMS_N * 4];
    __shared__ int   s_rk[NMS_N];
    // sorted candidate arrays
    __shared__ float s_sc[NMS_N];
    __shared__ float s_bx[NMS_N * 4];
    __shared__ unsigned char s_keep[NMS_N];
    __shared__ unsigned int s_supc[NMS_TILE * NMS_TW];  // column masks, 2 KB
    __shared__ unsigned int s_kwds[NMS_TW];             // published keep bits
    __shared__ int s_m;
    __shared__ int s_part[256];
    __shared__ int s_total;
    __shared__ int s_chg;

    if (threadIdx.x == 0) s_m = 0;
    __syncthreads();

    // --- wave-aggregated compact of class-c candidates (score > TH);
    //     s_rk zeroing fused into the same phase (covered by one barrier) ---
    const float2* p2 = (const float2*)p;   // row i = p2[3i], p2[3i+1], p2[3i+2]
    for (int i = threadIdx.x; i < NMS_N; i += blockDim.x) {   // uniform trips
        s_rk[i] = 0;                 // fused zero-init (rank phase reads after barrier)
        float2 v0 = p2[i * 3 + 0];   // x1, y1
        float2 v1 = p2[i * 3 + 1];   // x2, y2
        float2 v2 = p2[i * 3 + 2];   // cls, score
        const bool ok = ((int)v2.x == c) && (v2.y > NMS_SCORE_TH);
        unsigned long long mask = __ballot(ok);
        const int lane = threadIdx.x & 63;
        int base = 0;
        if (lane == 0) {
            int cnt = __popcll(mask);
            if (cnt) base = atomicAdd(&s_m, cnt);
        }
        base = __shfl(base, 0, 64);
        if (ok) {
            int pos = base + __popcll(mask & ((1ull << lane) - 1ull));
            s_scu[pos] = v2.y;
            s_ixu[pos] = i;
            s_bxu[pos * 4 + 0] = v0.x;
            s_bxu[pos * 4 + 1] = v0.y;
            s_bxu[pos * 4 + 2] = v1.x;
            s_bxu[pos * 4 + 3] = v1.y;
        }
    }
    __syncthreads();
    const int M = s_m;

    // --- task-parallel rank sort (r16-proven; s_rk pre-zeroed above) ---
    {
        const int nch = (M + 31) >> 5;
        const int ntask = M * nch;
        for (int task = threadIdx.x; task < ntask; task += blockDim.x) {
            const int q = task % M;          // consecutive tids -> distinct q
            const int ch = task / M;
            const float sq = s_scu[q];
            const int   iq = s_ixu[q];
            const int j0 = ch << 5;
            int jend = j0 + 32; if (jend > M) jend = M;
            int rk = 0;
            for (int j = j0; j < jend; ++j) {
                float sj = s_scu[j];
                rk += (sj > sq) || (sj == sq && s_ixu[j] < iq);
            }
            if (rk) atomicAdd(&s_rk[q], rk);
        }
    }
    __syncthreads();
    for (int q = threadIdx.x; q < M; q += blockDim.x) {
        int rk = s_rk[q];
        s_sc[rk] = s_scu[q];
        s_bx[rk * 4 + 0] = s_bxu[q * 4 + 0];
        s_bx[rk * 4 + 1] = s_bxu[q * 4 + 1];
        s_bx[rk * 4 + 2] = s_bxu[q * 4 + 2];
        s_bx[rk * 4 + 3] = s_bxu[q * 4 + 3];
        s_keep[rk] = 1;
    }
    __syncthreads();

    // --- tiled NMS: column masks + Jacobi fixpoint per tile (r15-proven) ---
    for (int t0 = 0; t0 < M; t0 += NMS_TILE) {
        const int tm = (M - t0 < NMS_TILE) ? (M - t0) : NMS_TILE;

        // A0: suppression by kept candidates of earlier tiles (final state)
        if (t0 > 0) {
            for (int j = threadIdx.x; j < tm; j += blockDim.x) {
                const int gj = t0 + j;
                float jx1 = s_bx[gj * 4 + 0], jy1 = s_bx[gj * 4 + 1];
                float jx2 = s_bx[gj * 4 + 2], jy2 = s_bx[gj * 4 + 3];
                float aj = (jy2 - jy1) * (jx2 - jx1);
                int dead = 0;
                for (int i = 0; i < t0 && !dead; ++i) {
                    if (!s_keep[i]) continue;
                    float ix1 = s_bx[i * 4 + 0], iy1 = s_bx[i * 4 + 1];
                    float ix2 = s_bx[i * 4 + 2], iy2 = s_bx[i * 4 + 3];
                    float ai = (iy2 - iy1) * (ix2 - ix1);
                    float ih = fminf(iy2, jy2) - fmaxf(iy1, jy1);
                    ih = fmaxf(ih, 0.0f);
                    float iw = fminf(ix2, jx2) - fmaxf(ix1, jx1);
                    iw = fmaxf(iw, 0.0f);
                    float inter = ih * iw;
                    float uni = ai + aj - inter;
                    float iou = (inter > 0.0f) ? inter / fmaxf(uni, 1e-08f) : 0.0f;
                    dead = iou > NMS_IOU_TH;
                }
                if (dead) s_keep[gj] = 0;
            }
            __syncthreads();
        }

        // A: column suppressor masks — (wi, j) task space in one sweep
        for (int idx = threadIdx.x; idx < NMS_TW * tm; idx += blockDim.x) {
            const int wi = idx / tm;
            const int j = idx % tm;
            const int ibase = wi << 5;
            unsigned int msk = 0;
            int iend = j - ibase;            // only i < j
            if (iend > 32) iend = 32;
            if (iend > 0) {
                const int gj = t0 + j;
                float jx1 = s_bx[gj * 4 + 0], jy1 = s_bx[gj * 4 + 1];
                float jx2 = s_bx[gj * 4 + 2], jy2 = s_bx[gj * 4 + 3];
                float aj = (jy2 - jy1) * (jx2 - jx1);
                for (int bb = 0; bb < iend; ++bb) {
                    const int gi = t0 + ibase + bb;
                    float ix1 = s_bx[gi * 4 + 0], iy1 = s_bx[gi * 4 + 1];
                    float ix2 = s_bx[gi * 4 + 2], iy2 = s_bx[gi * 4 + 3];
                    float ai = (iy2 - iy1) * (ix2 - ix1);
                    float ih = fminf(iy2, jy2) - fmaxf(iy1, jy1);
                    ih = fmaxf(ih, 0.0f);
                    float iw = fminf(ix2, jx2) - fmaxf(ix1, jx1);
                    iw = fmaxf(iw, 0.0f);
                    float inter = ih * iw;
                    float uni = ai + aj - inter;
                    float iou = (inter > 0.0f) ? inter / fmaxf(uni, 1e-08f) : 0.0f;
                    if (iou > NMS_IOU_TH) msk |= (1u << bb);
                }
            }
            s_supc[j * NMS_TW + wi] = msk;
        }

        // Jacobi init: thread j owns tile candidate j
        const int j = threadIdx.x;
        int ext = 0;                 // pre-suppression state (A0 deaths final)
        if (j < tm) ext = s_keep[t0 + j];
        int alive = ext;
        __syncthreads();             // supc complete

        {
            unsigned long long bal = __ballot(alive != 0);
            if ((threadIdx.x & 63) == 0 && threadIdx.x < NMS_TILE) {
                s_kwds[(threadIdx.x >> 6) * 2 + 0] = (unsigned int)(bal & 0xffffffffu);
                s_kwds[(threadIdx.x >> 6) * 2 + 1] = (unsigned int)(bal >> 32);
            }
            if (threadIdx.x == 0) s_chg = 0;
        }
        __syncthreads();

        int prev = 0;
        for (int round = 0; round < tm; ++round) {
            int newalive = 0;
            if (j < tm && ext) {
                unsigned int any = (s_supc[j * NMS_TW + 0] & s_kwds[0])
                                 | (s_supc[j * NMS_TW + 1] & s_kwds[1])
                                 | (s_supc[j * NMS_TW + 2] & s_kwds[2])
                                 | (s_supc[j * NMS_TW + 3] & s_kwds[3]);
                newalive = (any == 0);
            }
            int ch = (newalive != alive);
            alive = newalive;
            __syncthreads();                       // kwds reads done
            {
                unsigned long long bal = __ballot(alive != 0);
                if ((threadIdx.x & 63) == 0 && threadIdx.x < NMS_TILE) {
                    s_kwds[(threadIdx.x >> 6) * 2 + 0] = (unsigned int)(bal & 0xffffffffu);
                    s_kwds[(threadIdx.x >> 6) * 2 + 1] = (unsigned int)(bal >> 32);
                }
                if (ch) atomicAdd(&s_chg, 1);
            }
            __syncthreads();                       // kwds + counter visible
            int cur = s_chg;
            if (cur == prev) break;                // uniform decision
            prev = cur;
        }

        if (j < tm) s_keep[t0 + j] = (unsigned char)alive;
        __syncthreads();
    }

    // --- emit top-100 kept in sorted order (first 256 threads; r12-proven) ---
    const int chunk = (M + 255) / 256;           // contiguous slots per thread
    int lo = 0, hi = 0;
    if (threadIdx.x < 256) {
        lo = threadIdx.x * chunk;
        hi = (lo + chunk < M) ? (lo + chunk) : M;
        int cnt = 0;
        for (int jj = lo; jj < hi; ++jj) cnt += s_keep[jj];
        s_part[threadIdx.x] = cnt;
    }
    __syncthreads();
    if (threadIdx.x < 64) {
        const int base = threadIdx.x * 4;
        int v0 = s_part[base + 0], v1 = s_part[base + 1];
        int v2 = s_part[base + 2], v3 = s_part[base + 3];
        int sum = v0 + v1 + v2 + v3;
        int inc = sum;
        for (int off = 1; off < 64; off <<= 1) {
            int n = __shfl_up(inc, off, 64);
            if ((int)threadIdx.x >= off) inc += n;
        }
        int exc = inc - sum;
        s_part[base + 0] = exc;
        s_part[base + 1] = exc + v0;
        s_part[base + 2] = exc + v0 + v1;
        s_part[base + 3] = exc + v0 + v1 + v2;
        if (threadIdx.x == 63) s_total = inc;
    }
    __syncthreads();

    float* osc = ws_scores + ((size_t)b * NMS_NUM_CLASSES + c) * NMS_MAX_PER_CLASS;
    float* obx = ws_boxes + (((size_t)b * NMS_NUM_CLASSES + c) * NMS_MAX_PER_CLASS) * 4;
    if (threadIdx.x < 256) {
        int pos = s_part[threadIdx.x];
        for (int jj = lo; jj < hi; ++jj) {
            if (s_keep[jj]) {
                if (pos < NMS_MAX_PER_CLASS) {
                    osc[pos] = s_sc[jj];
                    obx[pos * 4 + 0] = s_bx[jj * 4 + 0];
                    obx[pos * 4 + 1] = s_bx[jj * 4 + 1];
                    obx[pos * 4 + 2] = s_bx[jj * 4 + 2];
                    obx[pos * 4 + 3] = s_bx[jj * 4 + 3];
                }
                pos++;
            }
        }
    }
    // pad positions [total, 100) with -1
    if (threadIdx.x < NMS_MAX_PER_CLASS && threadIdx.x >= s_total)
        osc[threadIdx.x] = -1.0f;
}

// ---------------------------------------------------------------------------
// Kernel 2: one block per (image, class), 256 threads. Task-parallel partial
// ranks. BYTE-IDENTICAL to round-12 (passed, absmax 0).
// ---------------------------------------------------------------------------
__global__ __launch_bounds__(256) void nms_topk_kernel(
    const float* __restrict__ ws_scores,   // [B, 1600]
    const float* __restrict__ ws_boxes,    // [B, 1600, 4]
    float* __restrict__ out,               // [B*600] rows + [B] nvalid
    int B)
{
    const int b = blockIdx.x / NMS_NUM_CLASSES;
    const int c = blockIdx.x % NMS_NUM_CLASSES;
    const int cbase = c * NMS_MAX_PER_CLASS;
    __shared__ float s_sc[NMS_NS];
    __shared__ int s_rank[NMS_MAX_PER_CLASS];

    const float* isc = ws_scores + (size_t)b * NMS_NS;
    for (int t = threadIdx.x; t < NMS_NS; t += blockDim.x) s_sc[t] = isc[t];
    if (threadIdx.x < NMS_MAX_PER_CLASS) s_rank[threadIdx.x] = 0;
    __syncthreads();

    for (int task = threadIdx.x; task < NMS_MAX_PER_CLASS * 16; task += blockDim.x) {
        const int slot = task % NMS_MAX_PER_CLASS;
        const int chunk = task / NMS_MAX_PER_CLASS;
        const int flat = cbase + slot;
        const float s = s_sc[flat];
        const int j0 = chunk * 100;
        int rk = 0;
        for (int j = j0; j < j0 + 100; ++j) {
            float sj = s_sc[j];
            rk += (sj > s) || (sj == s && j < flat);
        }
        if (rk) atomicAdd(&s_rank[slot], rk);
    }
    __syncthreads();

    int is_top = 0;
    const int t = threadIdx.x;
    if (t < NMS_MAX_PER_CLASS) {
        const int slot = cbase + t;
        float s = s_sc[slot];
        if (s > NMS_SCORE_TH) {
            int rk = s_rank[t];
            if (rk < NMS_MAX_DET) {
                const float* bx = ws_boxes + ((size_t)b * NMS_NS + slot) * 4;
                float* row = out + (size_t)b * NMS_MAX_DET * 6 + rk * 6;
                row[0] = bx[0];
                row[1] = bx[1];
                row[2] = bx[2];
                row[3] = bx[3];
                row[4] = (float)c;
                row[5] = s;
                is_top = 1;
            }
        }
    }
    unsigned long long m = __ballot(is_top);
    if ((threadIdx.x & 63) == 0) {
        float cnt = (float)__popcll(m);
        if (cnt > 0.0f)
            atomicAdd(&out[(size_t)B * NMS_MAX_DET * 6 + b], cnt);
    }
}

extern "C" void kernel_launch(void* const* d_in, const int* in_sizes, int n_in,
                              void* d_out, int out_size, void* d_ws, size_t ws_size,
                              hipStream_t stream) {
    const float* pred = (const float*)d_in[0];
    const int B = in_sizes[0] / (NMS_N * 6);
    if (B <= 0) return;
    float* out = (float*)d_out;

    float* ws_scores = (float*)d_ws;
    float* ws_boxes = ws_scores + (size_t)B * NMS_NS;

    nms_per_class_kernel<<<dim3(B * NMS_NUM_CLASSES), dim3(1024), 0, stream>>>(
        pred, ws_scores, ws_boxes, out, B);
    nms_topk_kernel<<<dim3(B * NMS_NUM_CLASSES), dim3(256), 0, stream>>>(
        ws_scores, ws_boxes, out, B);
}